// Round 1
// baseline (1049.257 us; speedup 1.0000x reference)
//
#include <hip/hip_runtime.h>
#include <stdint.h>

#define N_ANCH 33600
#define BS 16
#define NCH 56
#define MAX_NMS 3000
#define MAX_DET 300
#define CONF_T 0.25f
#define IOU_T 0.7f
#define IMG 1280.0f
#define NW 47                         // 47*64 = 3008 >= 3000 bits
#define HIST_BINS 4097
#define HIST_STRIDE 4112
#define CAND_CAP 4096

// ---- ws layout (bytes) ----
#define OFF_HIST 0                                   // 16*4112*4 = 263168
#define OFF_CNT   (BS*HIST_STRIDE*4)                 // 16*4
#define OFF_KEPT  (OFF_CNT + 64)                     // 16*4
#define ZERO_BYTES (OFF_KEPT + 64)                   // memset region
#define OFF_B     ZERO_BYTES                         // 16*4
#define OFF_CAND  (OFF_B + 64)                       // 16*4096*8
#define OFF_OIDX  (OFF_CAND + BS*CAND_CAP*8)         // 16*3000*4
#define OFF_SC    (OFF_OIDX + BS*MAX_NMS*4)          // 16*3000*4
#define OFF_BOX   (OFF_SC + BS*MAX_NMS*4)            // 16*3000*16 (16B aligned)
#define OFF_SEL   (OFF_BOX + BS*MAX_NMS*16)          // 16*300*4

__device__ __forceinline__ int score_bucket(float c, uint32_t* bits_out) {
    if (!(c > CONF_T)) { *bits_out = 0u; return 0; }
    uint32_t bits = __float_as_uint(c);
    *bits_out = bits;
    int bucket = (int)(bits >> 12) - 0x3E800 + 1;
    bucket = bucket < 1 ? 1 : (bucket > 4096 ? 4096 : bucket);
    return bucket;
}

// ---------------- Phase 1: histogram of score buckets ----------------
__global__ void k_hist(const float* __restrict__ preds, int* __restrict__ hist) {
    int g = blockIdx.x * blockDim.x + threadIdx.x;
    if (g >= BS * N_ANCH) return;
    int b = g / N_ANCH, a = g - b * N_ANCH;
    float c = preds[(size_t)b * NCH * N_ANCH + 4 * N_ANCH + a];
    uint32_t bits;
    int bucket = score_bucket(c, &bits);
    if (bucket > 0) atomicAdd(&hist[b * HIST_STRIDE + bucket], 1);
}

// ---------------- Phase 2: per-image threshold-bucket scan ----------------
__global__ void k_scan(const int* __restrict__ hist, int* __restrict__ Bout) {
    __shared__ int hl[HIST_BINS];
    __shared__ int part[256];
    __shared__ int suf[256];
    int b = blockIdx.x, t = threadIdx.x;
    for (int i = t; i < HIST_BINS; i += 256) hl[i] = hist[b * HIST_STRIDE + i];
    __syncthreads();
    int s = 0;
    for (int k = 0; k < 16; k++) s += hl[1 + t * 16 + k];
    part[t] = s;
    __syncthreads();
    if (t == 0) {
        int run = 0;
        for (int i = 255; i >= 0; i--) { suf[i] = run; run += part[i]; }
        if (run < MAX_NMS) Bout[b] = 1;   // fewer than 3000 valid: take all
    }
    __syncthreads();
    int low = suf[t], hi = low + part[t];
    if (low < MAX_NMS && hi >= MAX_NMS) {           // crossing inside my segment
        int run = low;
        for (int k = 15; k >= 0; k--) {
            int bin = 1 + t * 16 + k;
            run += hl[bin];
            if (run >= MAX_NMS) { Bout[b] = bin; break; }
        }
    }
}

// ---------------- Phase 3: compact candidates >= threshold bucket ----------------
__global__ void k_compact(const float* __restrict__ preds, const int* __restrict__ Bthr,
                          int* __restrict__ cnt, unsigned long long* __restrict__ cand) {
    int g = blockIdx.x * blockDim.x + threadIdx.x;
    if (g >= BS * N_ANCH) return;
    int b = g / N_ANCH, a = g - b * N_ANCH;
    float c = preds[(size_t)b * NCH * N_ANCH + 4 * N_ANCH + a];
    uint32_t bits;
    int bucket = score_bucket(c, &bits);
    if (bucket >= Bthr[b] && bucket > 0) {
        int pos = atomicAdd(&cnt[b], 1);
        if (pos < CAND_CAP)
            cand[b * CAND_CAP + pos] =
                ((unsigned long long)bits << 32) | (uint32_t)(~(uint32_t)a);
    }
}

// ---------------- Phase 4: bitonic sort (desc) + gather top-3000 ----------------
__global__ void k_sort(const float* __restrict__ preds, const int* __restrict__ cnt,
                       const unsigned long long* __restrict__ cand,
                       int* __restrict__ oidx, float* __restrict__ sc_out,
                       float4* __restrict__ box_out) {
    __shared__ unsigned long long keys[CAND_CAP];
    int b = blockIdx.x, t = threadIdx.x;
    int n = cnt[b]; if (n > CAND_CAP) n = CAND_CAP;
    for (int i = t; i < CAND_CAP; i += 1024)
        keys[i] = (i < n) ? cand[b * CAND_CAP + i] : 0ull;
    __syncthreads();
    for (int k = 2; k <= CAND_CAP; k <<= 1) {
        for (int j = k >> 1; j > 0; j >>= 1) {
            for (int i = t; i < CAND_CAP; i += 1024) {
                int ixj = i ^ j;
                if (ixj > i) {
                    bool dir = ((i & k) == 0);   // descending overall
                    unsigned long long a = keys[i], bb = keys[ixj];
                    if ((a < bb) == dir) { keys[i] = bb; keys[ixj] = a; }
                }
            }
            __syncthreads();
        }
    }
    const float* p = preds + (size_t)b * NCH * N_ANCH;
    for (int s = t; s < MAX_NMS; s += 1024) {
        unsigned long long key = keys[s];
        uint32_t hibits = (uint32_t)(key >> 32);
        float score; float4 bx; int oi;
        if (hibits) {
            oi = (int)(~(uint32_t)key);
            score = __uint_as_float(hibits);
            float cx = p[0 * N_ANCH + oi], cy = p[1 * N_ANCH + oi];
            float w  = p[2 * N_ANCH + oi], h  = p[3 * N_ANCH + oi];
            bx.x = fminf(fmaxf(cx - w * 0.5f, 0.f), IMG);
            bx.y = fminf(fmaxf(cy - h * 0.5f, 0.f), IMG);
            bx.z = fminf(fmaxf(cx + w * 0.5f, 0.f), IMG);
            bx.w = fminf(fmaxf(cy + h * 0.5f, 0.f), IMG);
        } else {
            oi = 0; score = -1.0f; bx = make_float4(0.f, 0.f, 0.f, 0.f);
        }
        oidx[b * MAX_NMS + s] = oi;
        sc_out[b * MAX_NMS + s] = score;
        box_out[b * MAX_NMS + s] = bx;
    }
}

__device__ __forceinline__ float iou_pair(float4 bi, float ai, float4 bj) {
    float aj  = (bj.z - bj.x) * (bj.w - bj.y);
    float ltx = fmaxf(bi.x, bj.x), lty = fmaxf(bi.y, bj.y);
    float rbx = fminf(bi.z, bj.z), rby = fminf(bi.w, bj.w);
    float wx  = fmaxf(rbx - ltx, 0.f), wy = fmaxf(rby - lty, 0.f);
    float inter = wx * wy;
    return inter / (ai + aj - inter + 1e-9f);
}

// ---------------- Phase 5: chunked greedy NMS with early exit at 300 kept ----------
__global__ void k_nms(const float4* __restrict__ box_ws, const float* __restrict__ sc_ws,
                      int* __restrict__ sel_slot, int* __restrict__ kept_count) {
    __shared__ float4 lbox[MAX_NMS];
    __shared__ unsigned long long remv[NW];
    __shared__ unsigned long long diag[64];
    int b = blockIdx.x, t = threadIdx.x;
    if (t < NW) remv[t] = 0ull;
    __syncthreads();
    for (int j = t; j < MAX_NMS; j += 1024) {
        lbox[j] = box_ws[b * MAX_NMS + j];
        if (!(sc_ws[b * MAX_NMS + j] > CONF_T))
            atomicOr(&remv[j >> 6], 1ull << (j & 63));   // invalid = pre-suppressed
    }
    __syncthreads();
    int kc = 0;
    for (int c = 0; c < NW; c++) {
        // -- intra-chunk 64x64 IoU words --
        if (t < 64) diag[t] = 0ull;
        __syncthreads();
        {
            int il = t >> 4;
            int j0 = (t & 15) * 4;
            int i = c * 64 + il;
            if (i < MAX_NMS) {
                float4 bi = lbox[i];
                float ai = (bi.z - bi.x) * (bi.w - bi.y);
                unsigned long long m = 0ull;
                for (int q = 0; q < 4; q++) {
                    int jl = j0 + q, j = c * 64 + jl;
                    if (j > i && j < MAX_NMS) {
                        if (iou_pair(bi, ai, lbox[j]) > IOU_T) m |= 1ull << jl;
                    }
                }
                if (m) atomicOr(&diag[il], m);
            }
        }
        __syncthreads();
        // -- sequential greedy bit loop (redundant on all threads; fully uniform) --
        unsigned long long s = remv[c];
        unsigned long long keptmask = 0ull;
        int jmax = MAX_NMS - c * 64; if (jmax > 64) jmax = 64;
        bool full = false;
        for (int bb = 0; bb < jmax; bb++) {
            if (!((s >> bb) & 1ull)) {
                s |= diag[bb];
                keptmask |= 1ull << bb;
                if (t == 0) sel_slot[b * MAX_DET + kc] = c * 64 + bb;
                kc++;
                if (kc == MAX_DET) { full = true; break; }
            }
        }
        __syncthreads();
        if (full) break;                 // decisions for output rows are final
        // -- apply kept rows' suppression to all later boxes (parallel over j) --
        int jbase = (c + 1) * 64;
        if (jbase < MAX_NMS && keptmask) {
            unsigned long long km = keptmask;
            while (km) {
                int bb = __builtin_ctzll(km);
                km &= km - 1;
                int i = c * 64 + bb;
                float4 bi = lbox[i];
                float ai = (bi.z - bi.x) * (bi.w - bi.y);
                for (int j = jbase + t; j < MAX_NMS; j += 1024) {
                    if (iou_pair(bi, ai, lbox[j]) > IOU_T)
                        atomicOr(&remv[j >> 6], 1ull << (j & 63));
                }
            }
        }
        __syncthreads();
    }
    if (t == 0) kept_count[b] = kc;
}

// ---------------- Phase 6: write outputs (zeros beyond kept) ----------------
__global__ void k_out(const float* __restrict__ preds, const float4* __restrict__ box_ws,
                      const float* __restrict__ sc_ws, const int* __restrict__ oidx,
                      const int* __restrict__ sel_slot, const int* __restrict__ kept_count,
                      float* __restrict__ out) {
    int g = blockIdx.x * blockDim.x + threadIdx.x;
    if (g >= BS * MAX_DET * 64) return;
    int det = g >> 6, lane = g & 63;
    int b = det / MAX_DET, r = det - b * MAX_DET;
    int kc = kept_count[b];
    float* ob  = out;                       // (16,300,4)
    float* osc = out + BS * MAX_DET * 4;    // (16,300,1)
    float* okp = out + BS * MAX_DET * 5;    // (16,300,51)
    if (r < kc) {
        int s = sel_slot[b * MAX_DET + r];
        if (lane < 4) {
            float4 bx = box_ws[b * MAX_NMS + s];
            float v = (lane == 0) ? bx.x : (lane == 1) ? bx.y : (lane == 2) ? bx.z : bx.w;
            ob[det * 4 + lane] = v;
        } else if (lane == 4) {
            osc[det] = sc_ws[b * MAX_NMS + s];
        } else if (lane < 56) {
            int k = lane - 5;
            int oi = oidx[b * MAX_NMS + s];
            float v = preds[(size_t)b * NCH * N_ANCH + (size_t)(5 + k) * N_ANCH + oi];
            if (k < 2) v = fminf(fmaxf(v, 0.f), IMG);   // ref clips only cols 0,1
            okp[det * 51 + k] = v;
        }
    } else {
        if (lane < 4)       ob[det * 4 + lane] = 0.f;
        else if (lane == 4) osc[det] = 0.f;
        else if (lane < 56) okp[det * 51 + (lane - 5)] = 0.f;
    }
}

extern "C" void kernel_launch(void* const* d_in, const int* in_sizes, int n_in,
                              void* d_out, int out_size, void* d_ws, size_t ws_size,
                              hipStream_t stream) {
    const float* preds = (const float*)d_in[0];
    float* out = (float*)d_out;
    char* ws = (char*)d_ws;
    int* hist = (int*)(ws + OFF_HIST);
    int* cnt  = (int*)(ws + OFF_CNT);
    int* kept = (int*)(ws + OFF_KEPT);
    int* Bthr = (int*)(ws + OFF_B);
    unsigned long long* cand = (unsigned long long*)(ws + OFF_CAND);
    int* oidx = (int*)(ws + OFF_OIDX);
    float* sc = (float*)(ws + OFF_SC);
    float4* box = (float4*)(ws + OFF_BOX);
    int* sel = (int*)(ws + OFF_SEL);

    hipMemsetAsync(d_ws, 0, ZERO_BYTES, stream);
    int nthreads = BS * N_ANCH;
    k_hist<<<(nthreads + 255) / 256, 256, 0, stream>>>(preds, hist);
    k_scan<<<BS, 256, 0, stream>>>(hist, Bthr);
    k_compact<<<(nthreads + 255) / 256, 256, 0, stream>>>(preds, Bthr, cnt, cand);
    k_sort<<<BS, 1024, 0, stream>>>(preds, cnt, cand, oidx, sc, box);
    k_nms<<<BS, 1024, 0, stream>>>(box, sc, sel, kept);
    k_out<<<(BS * MAX_DET * 64 + 255) / 256, 256, 0, stream>>>(preds, box, sc, oidx, sel, kept, out);
}

// Round 2
// 515.268 us; speedup vs baseline: 2.0363x; 2.0363x over previous
//
#include <hip/hip_runtime.h>
#include <stdint.h>

#define N_ANCH 33600
#define BS 16
#define NCH 56
#define MAX_NMS 3000
#define MAX_DET 300
#define CONF_T 0.25f
#define IOU_T 0.7f
#define IMG 1280.0f
#define NW 47                         // 47*64 = 3008 >= 3000 bits
#define HIST_BINS 4097
#define HIST_STRIDE 4112
#define CAND_CAP 4096
#define CNT_STRIDE 32                 // pad cnt[b] to one 128B line per image

// ---- ws layout (bytes) ----
#define OFF_HIST 0                                   // 16*4112*4 = 263168
#define OFF_CNT   (BS*HIST_STRIDE*4)                 // 16*32*4 = 2048
#define OFF_KEPT  (OFF_CNT + BS*CNT_STRIDE*4)        // 16*4
#define ZERO_BYTES (OFF_KEPT + 64)                   // memset region
#define OFF_B     ZERO_BYTES                         // 16*4
#define OFF_CAND  (OFF_B + 64)                       // 16*4096*8
#define OFF_OIDX  (OFF_CAND + BS*CAND_CAP*8)         // 16*3000*4
#define OFF_SC    (OFF_OIDX + BS*MAX_NMS*4)          // 16*3000*4
#define OFF_BOX   (OFF_SC + BS*MAX_NMS*4)            // 16*3000*16 (16B aligned)
#define OFF_SEL   (OFF_BOX + BS*MAX_NMS*16)          // 16*300*4

__device__ __forceinline__ int score_bucket(float c, uint32_t* bits_out) {
    if (!(c > CONF_T)) { *bits_out = 0u; return 0; }
    uint32_t bits = __float_as_uint(c);
    *bits_out = bits;
    int bucket = (int)(bits >> 12) - 0x3E800 + 1;
    bucket = bucket < 1 ? 1 : (bucket > 4096 ? 4096 : bucket);
    return bucket;
}

// ---------------- Phase 1: histogram of score buckets ----------------
__global__ void k_hist(const float* __restrict__ preds, int* __restrict__ hist) {
    int g = blockIdx.x * blockDim.x + threadIdx.x;
    if (g >= BS * N_ANCH) return;
    int b = g / N_ANCH, a = g - b * N_ANCH;
    float c = preds[(size_t)b * NCH * N_ANCH + 4 * N_ANCH + a];
    uint32_t bits;
    int bucket = score_bucket(c, &bits);
    if (bucket > 0) atomicAdd(&hist[b * HIST_STRIDE + bucket], 1);
}

// ---------------- Phase 2: per-image threshold-bucket scan ----------------
__global__ void k_scan(const int* __restrict__ hist, int* __restrict__ Bout) {
    __shared__ int hl[HIST_BINS];
    __shared__ int part[256];
    __shared__ int suf[256];
    int b = blockIdx.x, t = threadIdx.x;
    for (int i = t; i < HIST_BINS; i += 256) hl[i] = hist[b * HIST_STRIDE + i];
    __syncthreads();
    int s = 0;
    for (int k = 0; k < 16; k++) s += hl[1 + t * 16 + k];
    part[t] = s;
    __syncthreads();
    if (t == 0) {
        int run = 0;
        for (int i = 255; i >= 0; i--) { suf[i] = run; run += part[i]; }
        if (run < MAX_NMS) Bout[b] = 1;   // fewer than 3000 valid: take all
    }
    __syncthreads();
    int low = suf[t], hi = low + part[t];
    if (low < MAX_NMS && hi >= MAX_NMS) {           // crossing inside my segment
        int run = low;
        for (int k = 15; k >= 0; k--) {
            int bin = 1 + t * 16 + k;
            run += hl[bin];
            if (run >= MAX_NMS) { Bout[b] = bin; break; }
        }
    }
}

// ---------------- Phase 3: compact candidates >= threshold bucket ----------------
// b is wave-uniform (N_ANCH % 64 == 0), so aggregate the counter bump per wave:
// one atomic per wave instead of ~60 lane-serialized RMWs on a single cacheline.
__global__ void k_compact(const float* __restrict__ preds, const int* __restrict__ Bthr,
                          int* __restrict__ cnt, unsigned long long* __restrict__ cand) {
    int g = blockIdx.x * blockDim.x + threadIdx.x;
    if (g >= BS * N_ANCH) return;
    int b = g / N_ANCH, a = g - b * N_ANCH;
    float c = preds[(size_t)b * NCH * N_ANCH + 4 * N_ANCH + a];
    uint32_t bits;
    int bucket = score_bucket(c, &bits);
    bool pred = (bucket > 0) && (bucket >= Bthr[b]);
    unsigned long long mask = __ballot(pred);
    if (mask == 0ull) return;
    int lane = threadIdx.x & 63;
    int before = __popcll(mask & ((1ull << lane) - 1ull));
    int total = __popcll(mask);
    int base = 0;
    if (lane == 0) base = atomicAdd(&cnt[b * CNT_STRIDE], total);
    base = __shfl(base, 0);
    if (pred) {
        int pos = base + before;
        if (pos < CAND_CAP)
            cand[b * CAND_CAP + pos] =
                ((unsigned long long)bits << 32) | (uint32_t)(~(uint32_t)a);
    }
}

// ---------------- Phase 4: bitonic sort (desc) + gather top-3000 ----------------
__global__ void k_sort(const float* __restrict__ preds, const int* __restrict__ cnt,
                       const unsigned long long* __restrict__ cand,
                       int* __restrict__ oidx, float* __restrict__ sc_out,
                       float4* __restrict__ box_out) {
    __shared__ unsigned long long keys[CAND_CAP];
    int b = blockIdx.x, t = threadIdx.x;
    int n = cnt[b * CNT_STRIDE]; if (n > CAND_CAP) n = CAND_CAP;
    for (int i = t; i < CAND_CAP; i += 1024)
        keys[i] = (i < n) ? cand[b * CAND_CAP + i] : 0ull;
    __syncthreads();
    for (int k = 2; k <= CAND_CAP; k <<= 1) {
        for (int j = k >> 1; j > 0; j >>= 1) {
            for (int i = t; i < CAND_CAP; i += 1024) {
                int ixj = i ^ j;
                if (ixj > i) {
                    bool dir = ((i & k) == 0);   // descending overall
                    unsigned long long a = keys[i], bb = keys[ixj];
                    if ((a < bb) == dir) { keys[i] = bb; keys[ixj] = a; }
                }
            }
            __syncthreads();
        }
    }
    const float* p = preds + (size_t)b * NCH * N_ANCH;
    for (int s = t; s < MAX_NMS; s += 1024) {
        unsigned long long key = keys[s];
        uint32_t hibits = (uint32_t)(key >> 32);
        float score; float4 bx; int oi;
        if (hibits) {
            oi = (int)(~(uint32_t)key);
            score = __uint_as_float(hibits);
            float cx = p[0 * N_ANCH + oi], cy = p[1 * N_ANCH + oi];
            float w  = p[2 * N_ANCH + oi], h  = p[3 * N_ANCH + oi];
            bx.x = fminf(fmaxf(cx - w * 0.5f, 0.f), IMG);
            bx.y = fminf(fmaxf(cy - h * 0.5f, 0.f), IMG);
            bx.z = fminf(fmaxf(cx + w * 0.5f, 0.f), IMG);
            bx.w = fminf(fmaxf(cy + h * 0.5f, 0.f), IMG);
        } else {
            oi = 0; score = -1.0f; bx = make_float4(0.f, 0.f, 0.f, 0.f);
        }
        oidx[b * MAX_NMS + s] = oi;
        sc_out[b * MAX_NMS + s] = score;
        box_out[b * MAX_NMS + s] = bx;
    }
}

__device__ __forceinline__ float iou_pair(float4 bi, float ai, float4 bj) {
    float aj  = (bj.z - bj.x) * (bj.w - bj.y);
    float ltx = fmaxf(bi.x, bj.x), lty = fmaxf(bi.y, bj.y);
    float rbx = fminf(bi.z, bj.z), rby = fminf(bi.w, bj.w);
    float wx  = fmaxf(rbx - ltx, 0.f), wy = fmaxf(rby - lty, 0.f);
    float inter = wx * wy;
    return inter / (ai + aj - inter + 1e-9f);
}

// ---------------- Phase 5: chunked greedy NMS with early exit at 300 kept ----------
__global__ void k_nms(const float4* __restrict__ box_ws, const float* __restrict__ sc_ws,
                      int* __restrict__ sel_slot, int* __restrict__ kept_count) {
    __shared__ float4 lbox[MAX_NMS];
    __shared__ unsigned long long remv[NW];
    __shared__ unsigned long long diag[64];
    int b = blockIdx.x, t = threadIdx.x;
    if (t < NW) remv[t] = 0ull;
    __syncthreads();
    for (int j = t; j < MAX_NMS; j += 1024) {
        lbox[j] = box_ws[b * MAX_NMS + j];
        if (!(sc_ws[b * MAX_NMS + j] > CONF_T))
            atomicOr(&remv[j >> 6], 1ull << (j & 63));   // invalid = pre-suppressed
    }
    __syncthreads();
    int kc = 0;
    for (int c = 0; c < NW; c++) {
        // -- intra-chunk 64x64 IoU words --
        if (t < 64) diag[t] = 0ull;
        __syncthreads();
        {
            int il = t >> 4;
            int j0 = (t & 15) * 4;
            int i = c * 64 + il;
            if (i < MAX_NMS) {
                float4 bi = lbox[i];
                float ai = (bi.z - bi.x) * (bi.w - bi.y);
                unsigned long long m = 0ull;
                for (int q = 0; q < 4; q++) {
                    int jl = j0 + q, j = c * 64 + jl;
                    if (j > i && j < MAX_NMS) {
                        if (iou_pair(bi, ai, lbox[j]) > IOU_T) m |= 1ull << jl;
                    }
                }
                if (m) atomicOr(&diag[il], m);
            }
        }
        __syncthreads();
        // -- sequential greedy bit loop (redundant on all threads; fully uniform) --
        unsigned long long s = remv[c];
        unsigned long long keptmask = 0ull;
        int jmax = MAX_NMS - c * 64; if (jmax > 64) jmax = 64;
        bool full = false;
        for (int bb = 0; bb < jmax; bb++) {
            if (!((s >> bb) & 1ull)) {
                s |= diag[bb];
                keptmask |= 1ull << bb;
                if (t == 0) sel_slot[b * MAX_DET + kc] = c * 64 + bb;
                kc++;
                if (kc == MAX_DET) { full = true; break; }
            }
        }
        __syncthreads();
        if (full) break;                 // decisions for output rows are final
        // -- apply kept rows' suppression to all later boxes (parallel over j) --
        int jbase = (c + 1) * 64;
        if (jbase < MAX_NMS && keptmask) {
            unsigned long long km = keptmask;
            while (km) {
                int bb = __builtin_ctzll(km);
                km &= km - 1;
                int i = c * 64 + bb;
                float4 bi = lbox[i];
                float ai = (bi.z - bi.x) * (bi.w - bi.y);
                for (int j = jbase + t; j < MAX_NMS; j += 1024) {
                    if (iou_pair(bi, ai, lbox[j]) > IOU_T)
                        atomicOr(&remv[j >> 6], 1ull << (j & 63));
                }
            }
        }
        __syncthreads();
    }
    if (t == 0) kept_count[b] = kc;
}

// ---------------- Phase 6: write outputs (zeros beyond kept) ----------------
__global__ void k_out(const float* __restrict__ preds, const float4* __restrict__ box_ws,
                      const float* __restrict__ sc_ws, const int* __restrict__ oidx,
                      const int* __restrict__ sel_slot, const int* __restrict__ kept_count,
                      float* __restrict__ out) {
    int g = blockIdx.x * blockDim.x + threadIdx.x;
    if (g >= BS * MAX_DET * 64) return;
    int det = g >> 6, lane = g & 63;
    int b = det / MAX_DET, r = det - b * MAX_DET;
    int kc = kept_count[b];
    float* ob  = out;                       // (16,300,4)
    float* osc = out + BS * MAX_DET * 4;    // (16,300,1)
    float* okp = out + BS * MAX_DET * 5;    // (16,300,51)
    if (r < kc) {
        int s = sel_slot[b * MAX_DET + r];
        if (lane < 4) {
            float4 bx = box_ws[b * MAX_NMS + s];
            float v = (lane == 0) ? bx.x : (lane == 1) ? bx.y : (lane == 2) ? bx.z : bx.w;
            ob[det * 4 + lane] = v;
        } else if (lane == 4) {
            osc[det] = sc_ws[b * MAX_NMS + s];
        } else if (lane < 56) {
            int k = lane - 5;
            int oi = oidx[b * MAX_NMS + s];
            float v = preds[(size_t)b * NCH * N_ANCH + (size_t)(5 + k) * N_ANCH + oi];
            if (k < 2) v = fminf(fmaxf(v, 0.f), IMG);   // ref clips only cols 0,1
            okp[det * 51 + k] = v;
        }
    } else {
        if (lane < 4)       ob[det * 4 + lane] = 0.f;
        else if (lane == 4) osc[det] = 0.f;
        else if (lane < 56) okp[det * 51 + (lane - 5)] = 0.f;
    }
}

extern "C" void kernel_launch(void* const* d_in, const int* in_sizes, int n_in,
                              void* d_out, int out_size, void* d_ws, size_t ws_size,
                              hipStream_t stream) {
    const float* preds = (const float*)d_in[0];
    float* out = (float*)d_out;
    char* ws = (char*)d_ws;
    int* hist = (int*)(ws + OFF_HIST);
    int* cnt  = (int*)(ws + OFF_CNT);
    int* kept = (int*)(ws + OFF_KEPT);
    int* Bthr = (int*)(ws + OFF_B);
    unsigned long long* cand = (unsigned long long*)(ws + OFF_CAND);
    int* oidx = (int*)(ws + OFF_OIDX);
    float* sc = (float*)(ws + OFF_SC);
    float4* box = (float4*)(ws + OFF_BOX);
    int* sel = (int*)(ws + OFF_SEL);

    hipMemsetAsync(d_ws, 0, ZERO_BYTES, stream);
    int nthreads = BS * N_ANCH;
    k_hist<<<(nthreads + 255) / 256, 256, 0, stream>>>(preds, hist);
    k_scan<<<BS, 256, 0, stream>>>(hist, Bthr);
    k_compact<<<(nthreads + 255) / 256, 256, 0, stream>>>(preds, Bthr, cnt, cand);
    k_sort<<<BS, 1024, 0, stream>>>(preds, cnt, cand, oidx, sc, box);
    k_nms<<<BS, 1024, 0, stream>>>(box, sc, sel, kept);
    k_out<<<(BS * MAX_DET * 64 + 255) / 256, 256, 0, stream>>>(preds, box, sc, oidx, sel, kept, out);
}

// Round 3
// 320.851 us; speedup vs baseline: 3.2702x; 1.6059x over previous
//
#include <hip/hip_runtime.h>
#include <stdint.h>

#define N_ANCH 33600
#define BS 16
#define NCH 56
#define MAX_NMS 3000
#define MAX_DET 300
#define CONF_T 0.25f
#define IOU_T 0.7f
#define IMG 1280.0f
#define NW 47                         // 47*64 = 3008 >= 3000 bits
#define HIST_BINS 4097
#define HIST_STRIDE 4112
#define CAND_CAP 4096
#define CNT_STRIDE 32                 // pad cnt[b] to one 128B line per image

// ---- ws layout (bytes) ----
#define OFF_HIST 0                                   // 16*4112*4 = 263168
#define OFF_CNT   (BS*HIST_STRIDE*4)                 // 16*32*4 = 2048
#define OFF_KEPT  (OFF_CNT + BS*CNT_STRIDE*4)        // 16*4
#define ZERO_BYTES (OFF_KEPT + 64)                   // memset region
#define OFF_B     ZERO_BYTES                         // 16*4
#define OFF_CAND  (OFF_B + 64)                       // 16*4096*8
#define OFF_OIDX  (OFF_CAND + BS*CAND_CAP*8)         // 16*3000*4
#define OFF_SC    (OFF_OIDX + BS*MAX_NMS*4)          // 16*3000*4
#define OFF_BOX   (OFF_SC + BS*MAX_NMS*4)            // 16*3000*16 (16B aligned)
#define OFF_SEL   (OFF_BOX + BS*MAX_NMS*16)          // 16*300*4

__device__ __forceinline__ int score_bucket(float c, uint32_t* bits_out) {
    if (!(c > CONF_T)) { *bits_out = 0u; return 0; }
    uint32_t bits = __float_as_uint(c);
    *bits_out = bits;
    int bucket = (int)(bits >> 12) - 0x3E800 + 1;
    bucket = bucket < 1 ? 1 : (bucket > 4096 ? 4096 : bucket);
    return bucket;
}

// ---------------- Phase 1: histogram of score buckets ----------------
__global__ void k_hist(const float* __restrict__ preds, int* __restrict__ hist) {
    int g = blockIdx.x * blockDim.x + threadIdx.x;
    if (g >= BS * N_ANCH) return;
    int b = g / N_ANCH, a = g - b * N_ANCH;
    float c = preds[(size_t)b * NCH * N_ANCH + 4 * N_ANCH + a];
    uint32_t bits;
    int bucket = score_bucket(c, &bits);
    if (bucket > 0) atomicAdd(&hist[b * HIST_STRIDE + bucket], 1);
}

// ---------------- Phase 2: per-image threshold-bucket scan ----------------
__global__ void k_scan(const int* __restrict__ hist, int* __restrict__ Bout) {
    __shared__ int hl[HIST_BINS];
    __shared__ int part[256];
    __shared__ int suf[256];
    int b = blockIdx.x, t = threadIdx.x;
    for (int i = t; i < HIST_BINS; i += 256) hl[i] = hist[b * HIST_STRIDE + i];
    __syncthreads();
    int s = 0;
    for (int k = 0; k < 16; k++) s += hl[1 + t * 16 + k];
    part[t] = s;
    __syncthreads();
    if (t == 0) {
        int run = 0;
        for (int i = 255; i >= 0; i--) { suf[i] = run; run += part[i]; }
        if (run < MAX_NMS) Bout[b] = 1;   // fewer than 3000 valid: take all
    }
    __syncthreads();
    int low = suf[t], hi = low + part[t];
    if (low < MAX_NMS && hi >= MAX_NMS) {           // crossing inside my segment
        int run = low;
        for (int k = 15; k >= 0; k--) {
            int bin = 1 + t * 16 + k;
            run += hl[bin];
            if (run >= MAX_NMS) { Bout[b] = bin; break; }
        }
    }
}

// ---------------- Phase 3: compact candidates >= threshold bucket ----------------
__global__ void k_compact(const float* __restrict__ preds, const int* __restrict__ Bthr,
                          int* __restrict__ cnt, unsigned long long* __restrict__ cand) {
    int g = blockIdx.x * blockDim.x + threadIdx.x;
    if (g >= BS * N_ANCH) return;
    int b = g / N_ANCH, a = g - b * N_ANCH;
    float c = preds[(size_t)b * NCH * N_ANCH + 4 * N_ANCH + a];
    uint32_t bits;
    int bucket = score_bucket(c, &bits);
    bool pred = (bucket > 0) && (bucket >= Bthr[b]);
    unsigned long long mask = __ballot(pred);
    if (mask == 0ull) return;
    int lane = threadIdx.x & 63;
    int before = __popcll(mask & ((1ull << lane) - 1ull));
    int total = __popcll(mask);
    int base = 0;
    if (lane == 0) base = atomicAdd(&cnt[b * CNT_STRIDE], total);
    base = __shfl(base, 0);
    if (pred) {
        int pos = base + before;
        if (pos < CAND_CAP)
            cand[b * CAND_CAP + pos] =
                ((unsigned long long)bits << 32) | (uint32_t)(~(uint32_t)a);
    }
}

// ---------------- Phase 4: bitonic sort (desc) + gather top-3000 ----------------
__global__ void k_sort(const float* __restrict__ preds, const int* __restrict__ cnt,
                       const unsigned long long* __restrict__ cand,
                       int* __restrict__ oidx, float* __restrict__ sc_out,
                       float4* __restrict__ box_out) {
    __shared__ unsigned long long keys[CAND_CAP];
    int b = blockIdx.x, t = threadIdx.x;
    int n = cnt[b * CNT_STRIDE]; if (n > CAND_CAP) n = CAND_CAP;
    for (int i = t; i < CAND_CAP; i += 1024)
        keys[i] = (i < n) ? cand[b * CAND_CAP + i] : 0ull;
    __syncthreads();
    for (int k = 2; k <= CAND_CAP; k <<= 1) {
        for (int j = k >> 1; j > 0; j >>= 1) {
            for (int i = t; i < CAND_CAP; i += 1024) {
                int ixj = i ^ j;
                if (ixj > i) {
                    bool dir = ((i & k) == 0);   // descending overall
                    unsigned long long a = keys[i], bb = keys[ixj];
                    if ((a < bb) == dir) { keys[i] = bb; keys[ixj] = a; }
                }
            }
            __syncthreads();
        }
    }
    const float* p = preds + (size_t)b * NCH * N_ANCH;
    for (int s = t; s < MAX_NMS; s += 1024) {
        unsigned long long key = keys[s];
        uint32_t hibits = (uint32_t)(key >> 32);
        float score; float4 bx; int oi;
        if (hibits) {
            oi = (int)(~(uint32_t)key);
            score = __uint_as_float(hibits);
            float cx = p[0 * N_ANCH + oi], cy = p[1 * N_ANCH + oi];
            float w  = p[2 * N_ANCH + oi], h  = p[3 * N_ANCH + oi];
            bx.x = fminf(fmaxf(cx - w * 0.5f, 0.f), IMG);
            bx.y = fminf(fmaxf(cy - h * 0.5f, 0.f), IMG);
            bx.z = fminf(fmaxf(cx + w * 0.5f, 0.f), IMG);
            bx.w = fminf(fmaxf(cy + h * 0.5f, 0.f), IMG);
        } else {
            oi = 0; score = -1.0f; bx = make_float4(0.f, 0.f, 0.f, 0.f);
        }
        oidx[b * MAX_NMS + s] = oi;
        sc_out[b * MAX_NMS + s] = score;
        box_out[b * MAX_NMS + s] = bx;
    }
}

__device__ __forceinline__ float iou_pair(float4 bi, float ai, float4 bj) {
    float aj  = (bj.z - bj.x) * (bj.w - bj.y);
    float ltx = fmaxf(bi.x, bj.x), lty = fmaxf(bi.y, bj.y);
    float rbx = fminf(bi.z, bj.z), rby = fminf(bi.w, bj.w);
    float wx  = fmaxf(rbx - ltx, 0.f), wy = fmaxf(rby - lty, 0.f);
    float inter = wx * wy;
    return inter / (ai + aj - inter + 1e-9f);
}

__device__ __forceinline__ unsigned long long readlane64(unsigned long long v, int lane) {
    uint32_t lo = (uint32_t)v, hi = (uint32_t)(v >> 32);
    uint32_t rlo = __builtin_amdgcn_readlane(lo, lane);
    uint32_t rhi = __builtin_amdgcn_readlane(hi, lane);
    return ((unsigned long long)rhi << 32) | (unsigned long long)rlo;
}

// ---------------- Phase 5: PULL-model greedy NMS, early exit at 300 kept ----------
// Kept list lives in LDS; each chunk tests its 64 boxes against the kept list
// (64*kc IoU) instead of pushing suppression to all 3000 later boxes.
__global__ void k_nms(const float4* __restrict__ box_ws, const float* __restrict__ sc_ws,
                      int* __restrict__ sel_slot, int* __restrict__ kept_count) {
    __shared__ float4 lbox[MAX_NMS];
    __shared__ float4 kbox[MAX_DET];
    __shared__ float  karea[MAX_DET];
    __shared__ unsigned long long pres[NW];     // bit set = pre-suppressed/invalid
    __shared__ unsigned long long diag[64];     // diag[i] = in-chunk j's suppressed by i
    __shared__ unsigned long long keptmask_sh;
    int b = blockIdx.x, t = threadIdx.x;
    if (t < NW) pres[t] = 0ull;
    __syncthreads();
    for (int j = t; j < MAX_NMS; j += 1024) {
        lbox[j] = box_ws[b * MAX_NMS + j];
        if (!(sc_ws[b * MAX_NMS + j] > CONF_T))
            atomicOr(&pres[j >> 6], 1ull << (j & 63));   // invalid = pre-suppressed
    }
    __syncthreads();
    int kc = 0;
    for (int c = 0; c < NW && kc < MAX_DET; c++) {
        int base = c * 64;
        if (t < 64) diag[t] = 0ull;
        __syncthreads();
        // -- step 1: suppression of chunk boxes by already-kept boxes (pull) --
        {
            int jl = t >> 4, kk = t & 15;
            int j = base + jl;
            if (j < MAX_NMS && kc > 0) {
                float4 bj = lbox[j];
                bool sup = false;
                for (int kidx = kk; kidx < kc; kidx += 16) {
                    if (iou_pair(kbox[kidx], karea[kidx], bj) > IOU_T) { sup = true; break; }
                }
                if (sup) atomicOr(&pres[c], 1ull << jl);
            }
        }
        // -- step 2: intra-chunk 64x64 IoU words --
        {
            int il = t >> 4;
            int j0 = (t & 15) * 4;
            int i = base + il;
            if (i < MAX_NMS) {
                float4 bi = lbox[i];
                float ai = (bi.z - bi.x) * (bi.w - bi.y);
                unsigned long long m = 0ull;
                for (int q = 0; q < 4; q++) {
                    int jl = j0 + q, j = base + jl;
                    if (j > i && j < MAX_NMS) {
                        if (iou_pair(bi, ai, lbox[j]) > IOU_T) m |= 1ull << jl;
                    }
                }
                if (m) atomicOr(&diag[il], m);
            }
        }
        __syncthreads();
        // -- step 3: greedy bit loop, wave 0 only, diag via readlane (no LDS chain) --
        if (t < 64) {
            unsigned long long mydiag = diag[t];
            unsigned long long s = pres[c];
            unsigned long long keptm = 0ull;
            int room = MAX_DET - kc;
            int jmax = MAX_NMS - base; if (jmax > 64) jmax = 64;
            for (int bb = 0; bb < jmax; bb++) {
                if (!((s >> bb) & 1ull)) {
                    s |= readlane64(mydiag, bb);
                    keptm |= 1ull << bb;
                    if (--room == 0) break;
                }
            }
            if (t == 0) keptmask_sh = keptm;
        }
        __syncthreads();
        // -- step 4: append kept boxes to the kept list --
        unsigned long long keptm = keptmask_sh;
        if (t < 64 && ((keptm >> t) & 1ull)) {
            int pos = kc + __popcll(keptm & ((1ull << t) - 1ull));
            float4 bx = lbox[base + t];
            kbox[pos] = bx;
            karea[pos] = (bx.z - bx.x) * (bx.w - bx.y);
            sel_slot[b * MAX_DET + pos] = base + t;
        }
        kc += __popcll(keptm);
        __syncthreads();
    }
    if (t == 0) kept_count[b] = kc;
}

// ---------------- Phase 6: write outputs (zeros beyond kept) ----------------
__global__ void k_out(const float* __restrict__ preds, const float4* __restrict__ box_ws,
                      const float* __restrict__ sc_ws, const int* __restrict__ oidx,
                      const int* __restrict__ sel_slot, const int* __restrict__ kept_count,
                      float* __restrict__ out) {
    int g = blockIdx.x * blockDim.x + threadIdx.x;
    if (g >= BS * MAX_DET * 64) return;
    int det = g >> 6, lane = g & 63;
    int b = det / MAX_DET, r = det - b * MAX_DET;
    int kc = kept_count[b];
    float* ob  = out;                       // (16,300,4)
    float* osc = out + BS * MAX_DET * 4;    // (16,300,1)
    float* okp = out + BS * MAX_DET * 5;    // (16,300,51)
    if (r < kc) {
        int s = sel_slot[b * MAX_DET + r];
        if (lane < 4) {
            float4 bx = box_ws[b * MAX_NMS + s];
            float v = (lane == 0) ? bx.x : (lane == 1) ? bx.y : (lane == 2) ? bx.z : bx.w;
            ob[det * 4 + lane] = v;
        } else if (lane == 4) {
            osc[det] = sc_ws[b * MAX_NMS + s];
        } else if (lane < 56) {
            int k = lane - 5;
            int oi = oidx[b * MAX_NMS + s];
            float v = preds[(size_t)b * NCH * N_ANCH + (size_t)(5 + k) * N_ANCH + oi];
            if (k < 2) v = fminf(fmaxf(v, 0.f), IMG);   // ref clips only cols 0,1
            okp[det * 51 + k] = v;
        }
    } else {
        if (lane < 4)       ob[det * 4 + lane] = 0.f;
        else if (lane == 4) osc[det] = 0.f;
        else if (lane < 56) okp[det * 51 + (lane - 5)] = 0.f;
    }
}

extern "C" void kernel_launch(void* const* d_in, const int* in_sizes, int n_in,
                              void* d_out, int out_size, void* d_ws, size_t ws_size,
                              hipStream_t stream) {
    const float* preds = (const float*)d_in[0];
    float* out = (float*)d_out;
    char* ws = (char*)d_ws;
    int* hist = (int*)(ws + OFF_HIST);
    int* cnt  = (int*)(ws + OFF_CNT);
    int* kept = (int*)(ws + OFF_KEPT);
    int* Bthr = (int*)(ws + OFF_B);
    unsigned long long* cand = (unsigned long long*)(ws + OFF_CAND);
    int* oidx = (int*)(ws + OFF_OIDX);
    float* sc = (float*)(ws + OFF_SC);
    float4* box = (float4*)(ws + OFF_BOX);
    int* sel = (int*)(ws + OFF_SEL);

    hipMemsetAsync(d_ws, 0, ZERO_BYTES, stream);
    int nthreads = BS * N_ANCH;
    k_hist<<<(nthreads + 255) / 256, 256, 0, stream>>>(preds, hist);
    k_scan<<<BS, 256, 0, stream>>>(hist, Bthr);
    k_compact<<<(nthreads + 255) / 256, 256, 0, stream>>>(preds, Bthr, cnt, cand);
    k_sort<<<BS, 1024, 0, stream>>>(preds, cnt, cand, oidx, sc, box);
    k_nms<<<BS, 1024, 0, stream>>>(box, sc, sel, kept);
    k_out<<<(BS * MAX_DET * 64 + 255) / 256, 256, 0, stream>>>(preds, box, sc, oidx, sel, kept, out);
}

// Round 4
// 259.895 us; speedup vs baseline: 4.0372x; 1.2345x over previous
//
#include <hip/hip_runtime.h>
#include <stdint.h>

#define N_ANCH 33600
#define BS 16
#define NCH 56
#define MAX_NMS 3000
#define MAX_DET 300
#define CONF_T 0.25f
#define IOU_T 0.7f
#define IMG 1280.0f
#define NW 47                         // 47*64 = 3008 >= 3000 bits
#define NBINS 4096
#define HIST_BINS 4097
#define S_STRIDE 4104                 // row stride (ints) for hist/start tables
#define CAP 4096                      // candidate array capacity per image

// ---- ws layout (bytes) ----
#define OFF_CURS 0                                   // 16*4096*4 = 262144 (zeroed)
#define OFF_KEPT (OFF_CURS + BS*NBINS*4)             // 64 (zeroed)
#define ZERO_BYTES (OFF_KEPT + 64)
#define OFF_HIST  ZERO_BYTES                         // 16*4104*4 (plain stores)
#define OFF_START (OFF_HIST + BS*S_STRIDE*4)         // 16*4104*4
#define OFF_B     (OFF_START + BS*S_STRIDE*4)        // 64
#define OFF_M     (OFF_B + 64)                       // 64
#define OFF_CAND  (OFF_M + 64)                       // 16*4096*8
#define OFF_SORT  (OFF_CAND + BS*CAP*8)              // 16*4096*8
#define OFF_OIDX  (OFF_SORT + BS*CAP*8)              // 16*3000*4
#define OFF_SC    (OFF_OIDX + BS*MAX_NMS*4)          // 16*3000*4
#define OFF_BOX   (OFF_SC + BS*MAX_NMS*4)            // 16*3000*16 (16B aligned)
#define OFF_SEL   (OFF_BOX + BS*MAX_NMS*16)          // 16*300*4

__device__ __forceinline__ int score_bucket(float c, uint32_t* bits_out) {
    if (!(c > CONF_T)) { *bits_out = 0u; return 0; }
    uint32_t bits = __float_as_uint(c);
    *bits_out = bits;
    int bucket = (int)(bits >> 12) - 0x3E800 + 1;
    bucket = bucket < 1 ? 1 : (bucket > NBINS ? NBINS : bucket);
    return bucket;
}

// ---- Phase 1: per-image LDS histogram + suffix-scan -> start offsets ----
__global__ void k_histscan(const float* __restrict__ preds, int* __restrict__ hist,
                           int* __restrict__ start, int* __restrict__ Bthr,
                           int* __restrict__ Mout) {
    __shared__ int hl[HIST_BINS];
    __shared__ int part[256];
    __shared__ int suf[256];
    int b = blockIdx.x, t = threadIdx.x;     // 1024 threads
    for (int i = t; i < HIST_BINS; i += 1024) hl[i] = 0;
    __syncthreads();
    const float* conf = preds + (size_t)b * NCH * N_ANCH + 4 * N_ANCH;
    for (int a = t; a < N_ANCH; a += 1024) {
        uint32_t bits;
        int bucket = score_bucket(conf[a], &bits);
        if (bucket > 0) atomicAdd(&hl[bucket], 1);
    }
    __syncthreads();
    if (t < 256) {
        int s = 0;
        for (int k = 0; k < 16; k++) s += hl[1 + t * 16 + k];
        part[t] = s;
    }
    __syncthreads();
    if (t == 0) {
        int run = 0;
        for (int i = 255; i >= 0; i--) { suf[i] = run; run += part[i]; }
        if (run < MAX_NMS) { Bthr[b] = 1; Mout[b] = run; }  // fewer than 3000 valid
    }
    __syncthreads();
    if (t < 256) {
        int run = suf[t];
        bool maycross = (run < MAX_NMS) && (run + part[t] >= MAX_NMS);
        bool done = false;
        for (int k = 15; k >= 0; k--) {
            int bin = 1 + t * 16 + k;
            start[b * S_STRIDE + bin] = run;
            hist[b * S_STRIDE + bin] = hl[bin];
            run += hl[bin];
            if (maycross && !done && run >= MAX_NMS) {
                Bthr[b] = bin; Mout[b] = run; done = true;
            }
        }
    }
}

// ---- Phase 2: scatter candidates >= threshold bucket to their final segment ----
__global__ void k_scatter(const float* __restrict__ preds, const int* __restrict__ Bthr,
                          const int* __restrict__ start, int* __restrict__ curs,
                          unsigned long long* __restrict__ cand) {
    int g = blockIdx.x * blockDim.x + threadIdx.x;
    if (g >= BS * N_ANCH) return;
    int b = g / N_ANCH, a = g - b * N_ANCH;
    float c = preds[(size_t)b * NCH * N_ANCH + 4 * N_ANCH + a];
    uint32_t bits;
    int bucket = score_bucket(c, &bits);
    if (bucket > 0 && bucket >= Bthr[b]) {
        int pos = start[b * S_STRIDE + bucket] + atomicAdd(&curs[b * NBINS + (bucket - 1)], 1);
        if (pos < CAP)
            cand[b * CAP + pos] =
                ((unsigned long long)bits << 32) | (uint32_t)(~(uint32_t)a);
    }
}

// ---- Phase 3: exact rank within each bucket segment (keys unique) ----
__global__ void k_rank(const int* __restrict__ Bthr, const int* __restrict__ start,
                       const int* __restrict__ hist,
                       const unsigned long long* __restrict__ cand,
                       unsigned long long* __restrict__ sorted) {
    int wid = (blockIdx.x * blockDim.x + threadIdx.x) >> 6;
    int lane = threadIdx.x & 63;
    if (wid >= BS * NBINS) return;
    int b = wid >> 12;
    int bin = (wid & (NBINS - 1)) + 1;
    if (bin < Bthr[b]) return;
    int s = start[b * S_STRIDE + bin];
    if (s >= MAX_NMS) return;                 // segment entirely below top-3000
    int n = hist[b * S_STRIDE + bin];
    if (n <= 0) return;
    if (s + n > CAP) n = CAP - s;             // cap-dropped tail (theoretical)
    const unsigned long long* seg = cand + b * CAP + s;
    unsigned long long* oseg = sorted + b * CAP + s;
    for (int e = lane; e < n; e += 64) {
        unsigned long long ke = seg[e];
        int r = 0;
        for (int j = 0; j < n; j++) r += (seg[j] > ke);
        oseg[r] = ke;
    }
}

// ---- Phase 4: gather boxes/scores for top-3000 in sorted order ----
__global__ void k_gather(const float* __restrict__ preds,
                         const unsigned long long* __restrict__ sorted,
                         const int* __restrict__ M,
                         int* __restrict__ oidx, float* __restrict__ sc_out,
                         float4* __restrict__ box_out) {
    int g = blockIdx.x * blockDim.x + threadIdx.x;
    if (g >= BS * MAX_NMS) return;
    int b = g / MAX_NMS, p = g - b * MAX_NMS;
    float score; float4 bx; int oi;
    if (p < M[b]) {
        unsigned long long key = sorted[b * CAP + p];
        const float* pr = preds + (size_t)b * NCH * N_ANCH;
        oi = (int)(~(uint32_t)key);
        score = __uint_as_float((uint32_t)(key >> 32));
        float cx = pr[0 * N_ANCH + oi], cy = pr[1 * N_ANCH + oi];
        float w  = pr[2 * N_ANCH + oi], h  = pr[3 * N_ANCH + oi];
        bx.x = fminf(fmaxf(cx - w * 0.5f, 0.f), IMG);
        bx.y = fminf(fmaxf(cy - h * 0.5f, 0.f), IMG);
        bx.z = fminf(fmaxf(cx + w * 0.5f, 0.f), IMG);
        bx.w = fminf(fmaxf(cy + h * 0.5f, 0.f), IMG);
    } else {
        oi = 0; score = -1.0f; bx = make_float4(0.f, 0.f, 0.f, 0.f);
    }
    oidx[b * MAX_NMS + p] = oi;
    sc_out[b * MAX_NMS + p] = score;
    box_out[b * MAX_NMS + p] = bx;
}

__device__ __forceinline__ float iou_pair(float4 bi, float ai, float4 bj) {
    float aj  = (bj.z - bj.x) * (bj.w - bj.y);
    float ltx = fmaxf(bi.x, bj.x), lty = fmaxf(bi.y, bj.y);
    float rbx = fminf(bi.z, bj.z), rby = fminf(bi.w, bj.w);
    float wx  = fmaxf(rbx - ltx, 0.f), wy = fmaxf(rby - lty, 0.f);
    float inter = wx * wy;
    return inter / (ai + aj - inter + 1e-9f);
}

__device__ __forceinline__ unsigned long long readlane64(unsigned long long v, int lane) {
    uint32_t lo = (uint32_t)v, hi = (uint32_t)(v >> 32);
    uint32_t rlo = __builtin_amdgcn_readlane(lo, lane);
    uint32_t rhi = __builtin_amdgcn_readlane(hi, lane);
    return ((unsigned long long)rhi << 32) | (unsigned long long)rlo;
}

// ---- Phase 5: PULL-model greedy NMS, early exit at 300 kept ----
__global__ void k_nms(const float4* __restrict__ box_ws, const float* __restrict__ sc_ws,
                      int* __restrict__ sel_slot, int* __restrict__ kept_count) {
    __shared__ float4 lbox[MAX_NMS];
    __shared__ float4 kbox[MAX_DET];
    __shared__ float  karea[MAX_DET];
    __shared__ unsigned long long pres[NW];
    __shared__ unsigned long long diag[64];
    __shared__ unsigned long long keptmask_sh;
    int b = blockIdx.x, t = threadIdx.x;
    if (t < NW) pres[t] = 0ull;
    __syncthreads();
    for (int j = t; j < MAX_NMS; j += 1024) {
        lbox[j] = box_ws[b * MAX_NMS + j];
        if (!(sc_ws[b * MAX_NMS + j] > CONF_T))
            atomicOr(&pres[j >> 6], 1ull << (j & 63));
    }
    __syncthreads();
    int kc = 0;
    for (int c = 0; c < NW && kc < MAX_DET; c++) {
        int base = c * 64;
        if (t < 64) diag[t] = 0ull;
        __syncthreads();
        {
            int jl = t >> 4, kk = t & 15;
            int j = base + jl;
            if (j < MAX_NMS && kc > 0) {
                float4 bj = lbox[j];
                bool sup = false;
                for (int kidx = kk; kidx < kc; kidx += 16) {
                    if (iou_pair(kbox[kidx], karea[kidx], bj) > IOU_T) { sup = true; break; }
                }
                if (sup) atomicOr(&pres[c], 1ull << jl);
            }
        }
        {
            int il = t >> 4;
            int j0 = (t & 15) * 4;
            int i = base + il;
            if (i < MAX_NMS) {
                float4 bi = lbox[i];
                float ai = (bi.z - bi.x) * (bi.w - bi.y);
                unsigned long long m = 0ull;
                for (int q = 0; q < 4; q++) {
                    int jl = j0 + q, j = base + jl;
                    if (j > i && j < MAX_NMS) {
                        if (iou_pair(bi, ai, lbox[j]) > IOU_T) m |= 1ull << jl;
                    }
                }
                if (m) atomicOr(&diag[il], m);
            }
        }
        __syncthreads();
        if (t < 64) {
            unsigned long long mydiag = diag[t];
            unsigned long long s = pres[c];
            unsigned long long keptm = 0ull;
            int room = MAX_DET - kc;
            int jmax = MAX_NMS - base; if (jmax > 64) jmax = 64;
            for (int bb = 0; bb < jmax; bb++) {
                if (!((s >> bb) & 1ull)) {
                    s |= readlane64(mydiag, bb);
                    keptm |= 1ull << bb;
                    if (--room == 0) break;
                }
            }
            if (t == 0) keptmask_sh = keptm;
        }
        __syncthreads();
        unsigned long long keptm = keptmask_sh;
        if (t < 64 && ((keptm >> t) & 1ull)) {
            int pos = kc + __popcll(keptm & ((1ull << t) - 1ull));
            float4 bx = lbox[base + t];
            kbox[pos] = bx;
            karea[pos] = (bx.z - bx.x) * (bx.w - bx.y);
            sel_slot[b * MAX_DET + pos] = base + t;
        }
        kc += __popcll(keptm);
        __syncthreads();
    }
    if (t == 0) kept_count[b] = kc;
}

// ---- Phase 6: write outputs (zeros beyond kept) ----
__global__ void k_out(const float* __restrict__ preds, const float4* __restrict__ box_ws,
                      const float* __restrict__ sc_ws, const int* __restrict__ oidx,
                      const int* __restrict__ sel_slot, const int* __restrict__ kept_count,
                      float* __restrict__ out) {
    int g = blockIdx.x * blockDim.x + threadIdx.x;
    if (g >= BS * MAX_DET * 64) return;
    int det = g >> 6, lane = g & 63;
    int b = det / MAX_DET, r = det - b * MAX_DET;
    int kc = kept_count[b];
    float* ob  = out;                       // (16,300,4)
    float* osc = out + BS * MAX_DET * 4;    // (16,300,1)
    float* okp = out + BS * MAX_DET * 5;    // (16,300,51)
    if (r < kc) {
        int s = sel_slot[b * MAX_DET + r];
        if (lane < 4) {
            float4 bx = box_ws[b * MAX_NMS + s];
            float v = (lane == 0) ? bx.x : (lane == 1) ? bx.y : (lane == 2) ? bx.z : bx.w;
            ob[det * 4 + lane] = v;
        } else if (lane == 4) {
            osc[det] = sc_ws[b * MAX_NMS + s];
        } else if (lane < 56) {
            int k = lane - 5;
            int oi = oidx[b * MAX_NMS + s];
            float v = preds[(size_t)b * NCH * N_ANCH + (size_t)(5 + k) * N_ANCH + oi];
            if (k < 2) v = fminf(fmaxf(v, 0.f), IMG);
            okp[det * 51 + k] = v;
        }
    } else {
        if (lane < 4)       ob[det * 4 + lane] = 0.f;
        else if (lane == 4) osc[det] = 0.f;
        else if (lane < 56) okp[det * 51 + (lane - 5)] = 0.f;
    }
}

extern "C" void kernel_launch(void* const* d_in, const int* in_sizes, int n_in,
                              void* d_out, int out_size, void* d_ws, size_t ws_size,
                              hipStream_t stream) {
    const float* preds = (const float*)d_in[0];
    float* out = (float*)d_out;
    char* ws = (char*)d_ws;
    int* curs  = (int*)(ws + OFF_CURS);
    int* kept  = (int*)(ws + OFF_KEPT);
    int* hist  = (int*)(ws + OFF_HIST);
    int* start = (int*)(ws + OFF_START);
    int* Bthr  = (int*)(ws + OFF_B);
    int* M     = (int*)(ws + OFF_M);
    unsigned long long* cand   = (unsigned long long*)(ws + OFF_CAND);
    unsigned long long* sorted = (unsigned long long*)(ws + OFF_SORT);
    int* oidx = (int*)(ws + OFF_OIDX);
    float* sc = (float*)(ws + OFF_SC);
    float4* box = (float4*)(ws + OFF_BOX);
    int* sel = (int*)(ws + OFF_SEL);

    hipMemsetAsync(d_ws, 0, ZERO_BYTES, stream);
    k_histscan<<<BS, 1024, 0, stream>>>(preds, hist, start, Bthr, M);
    k_scatter<<<(BS * N_ANCH + 255) / 256, 256, 0, stream>>>(preds, Bthr, start, curs, cand);
    k_rank<<<(BS * NBINS * 64) / 256, 256, 0, stream>>>(Bthr, start, hist, cand, sorted);
    k_gather<<<(BS * MAX_NMS + 255) / 256, 256, 0, stream>>>(preds, sorted, M, oidx, sc, box);
    k_nms<<<BS, 1024, 0, stream>>>(box, sc, sel, kept);
    k_out<<<(BS * MAX_DET * 64 + 255) / 256, 256, 0, stream>>>(preds, box, sc, oidx, sel, kept, out);
}